// Round 12
// baseline (287.884 us; speedup 1.0000x reference)
//
#include <hip/hip_runtime.h>
#include <hip/hip_bf16.h>
#include <cstddef>
#include <cstdint>

typedef unsigned short u16;
typedef unsigned int   u32;

#define Mtok  16384
#define Ncode 8192
#define Kdim  256
#define NSPL  128                 // splits (64 codes each, B-split = 32 KB LDS)
#define NPER  (Ncode / NSPL)      // 64 codes per split
#define NMT   (Mtok / 128)        // 128 m-tiles
#define TH_MARGIN 2.0f            // err budget: 2*(bf16 ~0.25 + pack ~0.5) = 1.5 < 2.0
#define RCHUNK 256                // full-rescue: codes per chunk
#define RNCH  (Ncode / RCHUNK)    // 32 chunks

typedef __bf16 bf16x8 __attribute__((ext_vector_type(8)));
typedef float  f32x4  __attribute__((ext_vector_type(4)));

#define LDSP(p) ((__attribute__((address_space(3))) void*)(p))
#define GPTR(p) ((const __attribute__((address_space(1))) void*)(p))

__device__ __forceinline__ u16 f2bf(float x) {
    __hip_bfloat16 h = __float2bfloat16(x);
    return *reinterpret_cast<u16*>(&h);
}

// ---------------------------------------------------------------------------
// Kernel 1: transpose z -> z_out (fp32), plus bf16 s = -2*z.
// Also zeroes the rescue counter (stream-ordered before k_merge).
__global__ __launch_bounds__(256) void k_prep(const float* __restrict__ z,
        float* __restrict__ z_out, u16* __restrict__ sh, int* __restrict__ count) {
    __shared__ float tile[32][33];
    const int b  = blockIdx.z;
    const int c0 = blockIdx.y * 32;
    const int p0 = blockIdx.x * 32;
    const int tx = threadIdx.x;   // 0..31
    const int ty = threadIdx.y;   // 0..7
    if (b == 0 && c0 == 0 && p0 == 0 && tx == 0 && ty == 0) count[0] = 0;
    const float* src = z + ((size_t)b * Kdim + c0) * 1024 + p0;
#pragma unroll
    for (int i = 0; i < 32; i += 8)
        tile[ty + i][tx] = src[(size_t)(ty + i) * 1024 + tx];
    __syncthreads();
#pragma unroll
    for (int i = 0; i < 32; i += 8) {
        const float v = tile[tx][ty + i];
        const size_t m = (size_t)b * 1024 + p0 + ty + i;
        const int    c = c0 + tx;
        z_out[m * Kdim + c] = v;
        sh[m * Kdim + c] = f2bf(-2.0f * v);
    }
}

// ---------------------------------------------------------------------------
// Kernel 2: per-code ||w||^2 plus bf16 wh. One wave per code row.
__global__ __launch_bounds__(64) void k_wsplit(const float* __restrict__ w,
        float* __restrict__ wnorm, u16* __restrict__ wh) {
    const int row  = blockIdx.x;
    const int lane = threadIdx.x;
    const float4 v = ((const float4*)(w + (size_t)row * Kdim))[lane];
    float s = v.x * v.x + v.y * v.y + v.z * v.z + v.w * v.w;
#pragma unroll
    for (int off = 32; off > 0; off >>= 1)
        s += __shfl_down(s, off, 64);
    if (lane == 0) wnorm[row] = s;
    ushort4 ph;
    u16* hp = (u16*)&ph;
    hp[0] = f2bf(v.x); hp[1] = f2bf(v.y); hp[2] = f2bf(v.z); hp[3] = f2bf(v.w);
    *(ushort4*)(wh + (size_t)row * Kdim + lane * 4) = ph;
}

// ---------------------------------------------------------------------------
// Kernel 3 (round-14): zero-pipeline resident-split, FIXED geometry +
// occupancy. Round-11 regression diagnosed: 512-B LDS rows defeat the 8-chunk
// swizzle (row bits don't touch bank selection at that stride) -> 4-way
// conflict (SQ_LDS_BANK_CONFLICT = 2^23 exactly). Fix: store the split as 4
// K-sub-tiles Bs[4][64][64 u16] -- 128-B rows, the byte-identical geometry
// + swizzle (chunk ^ (row&7), pre-swizzled source, 8-row gload_lds groups)
// that measured ZERO conflicts in rounds 8-10.
// Occupancy: NPER 128->64 => 32 KB LDS => 5 blocks/CU (was 2), 20 waves/CU
// to overlap the latency-bound stage->read->MFMA chain (both pipes <50%).
// PACKED-KEY top-3 kept (proven r11): key = (bits(max(d,0)) & ~0x1FFF)|idx;
// sorted-3 insert = 5 min/max ops; truncation <= 0.5 absorbed by TH=2.0.
__global__ __launch_bounds__(256, 2) void k_mfma(
        const u16* __restrict__ sh, const u16* __restrict__ wh,
        const float* __restrict__ wnorm,
        float* __restrict__ pk1, float* __restrict__ pk2, float* __restrict__ pk3) {
    __shared__ __align__(16) u16 Bs[4 * NPER * 64];   // 4 subtiles x 64 rows x 64 u16 = 32 KB
    const int tid  = threadIdx.x;
    const int w    = tid >> 6;          // wave 0..3
    const int lane = tid & 63;
    const int l15  = lane & 15;
    const int q    = lane >> 4;         // 0..3
    const int x    = blockIdx.x & (NMT - 1);    // m-tile (XCD pin: sh slice L2-fit)
    const int y    = blockIdx.x >> 7;           // split
    const int m0   = x * 128;
    const int n0   = y * NPER;
    const int srow8 = lane >> 3;        // staging: 8 rows x 8 16B-chunks
    const int sqg8  = (lane & 7) ^ srow8;  // pre-swizzled source chunk (row&7 == srow8)
    const int rsw   = l15 & 7;             // read-side row swizzle bits

    // ---- stage whole B-split -> LDS as 4 K-sub-tiles (proven r10 geometry) --
    // sub-tile kb holds k = kb*64 .. kb*64+63 for all 64 codes; rows 128 B.
#pragma unroll
    for (int kb = 0; kb < 4; ++kb) {
#pragma unroll
        for (int c = 0; c < 2; ++c) {
            const int baser = w * 16 + c * 8;            // 8-row group, %8 == 0
            const size_t gb = (size_t)(n0 + baser + srow8) * Kdim
                              + kb * 64 + sqg8 * 8;
            __builtin_amdgcn_global_load_lds(GPTR(wh + gb),
                LDSP(Bs + (kb * NPER + baser) * 64), 16, 0, 0);
        }
    }
    // ---- A fragments -> registers (64 VGPR) ----
    bf16x8 ah[8][2];
#pragma unroll
    for (int ks = 0; ks < 8; ++ks)
#pragma unroll
        for (int i = 0; i < 2; ++i) {
            const size_t ra = (size_t)(m0 + w * 32 + i * 16 + l15) * Kdim
                              + ks * 32 + q * 8;
            ah[ks][i] = *(const bf16x8*)(sh + ra);
        }
    // ---- wnorm for this split's columns -> regs (L2-hot) ----
    float wn_r[4];
#pragma unroll
    for (int j = 0; j < 4; ++j) wn_r[j] = wnorm[n0 + j * 16 + l15];

    asm volatile("s_waitcnt vmcnt(0)" ::: "memory");
    __builtin_amdgcn_s_barrier();       // the ONLY barrier

    // ---- compute: 32 ds_read + 64 MFMA, sync-free ----
    f32x4 acc[2][4];
#pragma unroll
    for (int j = 0; j < 4; ++j) {
        const float wv = wn_r[j];
#pragma unroll
        for (int i = 0; i < 2; ++i) {
            acc[i][j][0] = wv; acc[i][j][1] = wv;
            acc[i][j][2] = wv; acc[i][j][3] = wv;
        }
    }
    __builtin_amdgcn_s_setprio(1);
#pragma unroll
    for (int ks = 0; ks < 8; ++ks) {
        const int kb = ks >> 1;                          // sub-tile
        const int cbase = (ks & 1) * 4 + q;              // within-tile chunk
#pragma unroll
        for (int j = 0; j < 4; ++j) {
            const int ro = (kb * NPER + j * 16 + l15) * 64 + ((cbase ^ rsw) * 8);
            const bf16x8 bh_ = *(const bf16x8*)&Bs[ro];
            acc[0][j] = __builtin_amdgcn_mfma_f32_16x16x32_bf16(ah[ks][0], bh_, acc[0][j], 0, 0, 0);
            acc[1][j] = __builtin_amdgcn_mfma_f32_16x16x32_bf16(ah[ks][1], bh_, acc[1][j], 0, 0, 0);
        }
    }
    __builtin_amdgcn_s_setprio(0);

    // ---- packed-key top-3: slot s=i*4+r -> row m0+w*32+i*16+q*4+r ----
    int jk[4];
#pragma unroll
    for (int j = 0; j < 4; ++j) jk[j] = n0 + j * 16 + l15;   // 13-bit global idx
    const float SENT = __uint_as_float(0x7F7FFFFFu);
    float k1[8], k2[8], k3[8];
#pragma unroll
    for (int s = 0; s < 8; ++s) { k1[s] = SENT; k2[s] = SENT; k3[s] = SENT; }
#pragma unroll
    for (int i = 0; i < 2; ++i)
#pragma unroll
        for (int r = 0; r < 4; ++r) {
            const int s = i * 4 + r;
#pragma unroll
            for (int j = 0; j < 4; ++j) {
                const u32 kb = (__float_as_uint(fmaxf(acc[i][j][r], 0.0f))
                                & 0xFFFFE000u) | (u32)jk[j];
                const float p = __uint_as_float(kb);
                const float nk1 = fminf(k1[s], p);
                const float nk2 = fminf(k2[s], fmaxf(k1[s], p));
                const float nk3 = fminf(k3[s], fmaxf(k2[s], p));
                k1[s] = nk1; k2[s] = nk2; k3[s] = nk3;
            }
        }
    // butterfly merge of sorted triples across the 16 row-lanes
#pragma unroll
    for (int msk = 1; msk < 16; msk <<= 1) {
#pragma unroll
        for (int s = 0; s < 8; ++s) {
            const float b1 = __shfl_xor(k1[s], msk, 64);
            const float b2 = __shfl_xor(k2[s], msk, 64);
            const float b3 = __shfl_xor(k3[s], msk, 64);
            const float w1 = fminf(k1[s], b1);
            const float w2 = fminf(fmaxf(k1[s], b1), fminf(k2[s], b2));
            const float w3 = fminf(fminf(fmaxf(k2[s], b1), fmaxf(k1[s], b2)),
                                   fminf(k3[s], b3));
            k1[s] = w1; k2[s] = w2; k3[s] = w3;
        }
    }
    if (l15 == 0) {
#pragma unroll
        for (int i = 0; i < 2; ++i)
#pragma unroll
            for (int r = 0; r < 4; ++r) {
                const int s = i * 4 + r;
                const int m = m0 + w * 32 + i * 16 + q * 4 + r;
                pk1[(size_t)y * Mtok + m] = k1[s];
                pk2[(size_t)y * Mtok + m] = k2[s];
                pk3[(size_t)y * Mtok + m] = k3[s];
            }
    }
}

// ---------------------------------------------------------------------------
// Kernel 4: merge split top-3 keys -> resolved idx OR candidates OR full.
// Keys are value-packed (idx in low 13 bits) -> pure fmin compares.
// full if any split's 3rd key inside the window or candidate overflow.
__global__ __launch_bounds__(256) void k_merge(
        const float* __restrict__ pk1, const float* __restrict__ pk2,
        const float* __restrict__ pk3, int* __restrict__ fidx,
        int* __restrict__ flag, int* __restrict__ cands,
        int* __restrict__ list, int* __restrict__ count) {
    const int t = blockIdx.x * 256 + threadIdx.x;
    float gb1 = __uint_as_float(0x7F7FFFFFu);
#pragma unroll 8
    for (int s = 0; s < NSPL; ++s)
        gb1 = fminf(gb1, pk1[(size_t)s * Mtok + t]);
    const float lim = __uint_as_float(__float_as_uint(gb1) & 0xFFFFE000u)
                      + TH_MARGIN;
    bool full = false;
    int nc = 0;
#pragma unroll 8
    for (int s = 0; s < NSPL; ++s) {
        const float a1 = pk1[(size_t)s * Mtok + t];
        const float a2 = pk2[(size_t)s * Mtok + t];
        const float a3 = pk3[(size_t)s * Mtok + t];
        if (a1 < lim) {
            if (nc < 16) cands[(size_t)t * 16 + nc] = (int)(__float_as_uint(a1) & 0x1FFFu);
            ++nc;
        }
        if (a2 < lim) {
            if (nc < 16) cands[(size_t)t * 16 + nc] = (int)(__float_as_uint(a2) & 0x1FFFu);
            ++nc;
        }
        full = full || (a3 < lim);
    }
    if (nc > 16) full = true;
    fidx[t] = (int)(__float_as_uint(gb1) & 0x1FFFu);
    int f = 0;
    if (full) {
        f = -1;
        const int p = atomicAdd(count, 1);
        list[p] = t;
    } else if (nc >= 2) {
        f = nc;
    }
    flag[t] = f;
}

// ---------------------------------------------------------------------------
// Kernel 5: exact fp32 full rescore (rare safety net), over code chunks.
__global__ __launch_bounds__(256) void k_rescue(
        const float* __restrict__ z_out, const float* __restrict__ w,
        const float* __restrict__ wnorm, const int* __restrict__ list,
        const int* __restrict__ count,
        float* __restrict__ pcv, int* __restrict__ pci) {
    const int bx   = blockIdx.x;       // chunk
    const int tid  = threadIdx.x;
    const int wv   = tid >> 6;
    const int lane = tid & 63;
    __shared__ float rv[4];
    __shared__ int   ri[4];
    const int cnt = count[0];
    for (int it = blockIdx.y; it < cnt; it += gridDim.y) {
        const int t = list[it];
        const float4 zv = *(const float4*)(z_out + (size_t)t * Kdim + lane * 4);
        float bd = 3.0e38f; int bn = 0x7fffffff;
#pragma unroll 4
        for (int i = 0; i < RCHUNK / 4; ++i) {
            const int n = bx * RCHUNK + i * 4 + wv;
            const float4 wr = *(const float4*)(w + (size_t)n * Kdim + lane * 4);
            float s = fmaf(wr.x, zv.x, fmaf(wr.y, zv.y,
                      fmaf(wr.z, zv.z, wr.w * zv.w)));
#pragma unroll
            for (int msk = 1; msk < 64; msk <<= 1)
                s += __shfl_xor(s, msk, 64);
            const float d = wnorm[n] - 2.0f * s;
            if (d < bd) { bd = d; bn = n; }
        }
        if (lane == 0) { rv[wv] = bd; ri[wv] = bn; }
        __syncthreads();
        if (tid == 0) {
            float b = rv[0]; int bi = ri[0];
#pragma unroll
            for (int k = 1; k < 4; ++k)
                if (rv[k] < b || (rv[k] == b && ri[k] < bi)) { b = rv[k]; bi = ri[k]; }
            pcv[(size_t)t * RNCH + bx] = b;
            pci[(size_t)t * RNCH + bx] = bi;
        }
        __syncthreads();
    }
}

// ---------------------------------------------------------------------------
// Kernel 6: gather z_q = weight[idx] + per-token resolution. One wave/token.
// flag==0: fidx. flag==n: exact fp32 rescore of the n candidates (wave
// butterfly dot, all lanes converge). flag==-1: merge RNCH full partials.
__global__ __launch_bounds__(256) void k_gather(
        const float* __restrict__ z_out, const float* __restrict__ w,
        const float* __restrict__ wnorm, const int* __restrict__ fidx,
        const int* __restrict__ flag, const int* __restrict__ cands,
        const float* __restrict__ pcv, const int* __restrict__ pci,
        float* __restrict__ zq, float* __restrict__ idx_out) {
    const int token = blockIdx.x * 4 + (threadIdx.x >> 6);
    const int lane  = threadIdx.x & 63;
    const int f = flag[token];
    int bi = fidx[token];
    if (f == -1) {
        float v = 3.0e38f; int ii = 0x7fffffff;
        if (lane < RNCH) {
            v  = pcv[(size_t)token * RNCH + lane];
            ii = pci[(size_t)token * RNCH + lane];
        }
#pragma unroll
        for (int msk = 1; msk < 64; msk <<= 1) {
            const float ov = __shfl_xor(v, msk, 64);
            const int   oi = __shfl_xor(ii, msk, 64);
            if (ov < v || (ov == v && oi < ii)) { v = ov; ii = oi; }
        }
        bi = ii;
    } else if (f > 0) {
        const float4 zv = *(const float4*)(z_out + (size_t)token * Kdim + lane * 4);
        float bv = 3.0e38f; int bn = 0x7fffffff;
#pragma unroll 1
        for (int c = 0; c < f; ++c) {
            const int n = cands[(size_t)token * 16 + c];
            const float4 wr = *(const float4*)(w + (size_t)n * Kdim + lane * 4);
            float s = fmaf(wr.x, zv.x, fmaf(wr.y, zv.y,
                      fmaf(wr.z, zv.z, wr.w * zv.w)));
#pragma unroll
            for (int msk = 1; msk < 64; msk <<= 1)
                s += __shfl_xor(s, msk, 64);
            const float d = wnorm[n] - 2.0f * s;
            if (d < bv || (d == bv && n < bn)) { bv = d; bn = n; }
        }
        bi = bn;   // uniform: butterfly gives all lanes the full sum
    }
    const float4 u = *(const float4*)(w + (size_t)bi * Kdim + lane * 4);
    *(float4*)(zq + (size_t)token * Kdim + lane * 4) = u;
    if (lane == 0) idx_out[token] = (float)bi;
}

// ---------------------------------------------------------------------------
extern "C" void kernel_launch(void* const* d_in, const int* in_sizes, int n_in,
                              void* d_out, int out_size, void* d_ws, size_t ws_size,
                              hipStream_t stream) {
    const float* z = (const float*)d_in[0];
    const float* w = (const float*)d_in[1];

    float* z_out  = (float*)d_out;                          // [16384, 256]
    float* zq     = z_out + (size_t)Mtok * Kdim;            // [16384, 256]
    float* idxout = zq + (size_t)Mtok * Kdim;               // [16384]

    char* ws = (char*)d_ws;
    u16*   sh    = (u16*)ws;                       ws += (size_t)Mtok * Kdim * 2;
    u16*   wh    = (u16*)ws;                       ws += (size_t)Ncode * Kdim * 2;
    float* wnorm = (float*)ws;                     ws += (size_t)Ncode * 4;
    float* pk1   = (float*)ws;                     ws += (size_t)NSPL * Mtok * 4;
    float* pk2   = (float*)ws;                     ws += (size_t)NSPL * Mtok * 4;
    float* pk3   = (float*)ws;                     ws += (size_t)NSPL * Mtok * 4;
    int*   fidx  = (int*)ws;                       ws += (size_t)Mtok * 4;
    int*   flag  = (int*)ws;                       ws += (size_t)Mtok * 4;
    int*   cands = (int*)ws;                       ws += (size_t)Mtok * 16 * 4;
    int*   list  = (int*)ws;                       ws += (size_t)Mtok * 4;
    int*   count = (int*)ws;                       ws += 256;
    // pcv/pci alias pk1/pk2: pk* are dead after k_merge, and k_rescue
    // (writer) / k_gather (reader) are stream-ordered after it.
    float* pcv   = pk1;                            // [Mtok, RNCH] = 2 MB, fits
    int*   pci   = (int*)pk2;

    k_prep<<<dim3(1024 / 32, Kdim / 32, 16), dim3(32, 8), 0, stream>>>(z, z_out, sh, count);
    k_wsplit<<<dim3(Ncode), dim3(64), 0, stream>>>(w, wnorm, wh);
    k_mfma<<<dim3(NSPL * NMT), dim3(256), 0, stream>>>(sh, wh, wnorm,
                                                       pk1, pk2, pk3);
    k_merge<<<dim3(Mtok / 256), dim3(256), 0, stream>>>(pk1, pk2, pk3,
                                                        fidx, flag, cands, list, count);
    k_rescue<<<dim3(RNCH, 64), dim3(256), 0, stream>>>(z_out, w, wnorm, list, count,
                                                       pcv, pci);
    k_gather<<<dim3(Mtok / 4), dim3(256), 0, stream>>>(z_out, w, wnorm, fidx, flag,
                                                       cands, pcv, pci, zq, idxout);
}

// Round 13
// 207.225 us; speedup vs baseline: 1.3892x; 1.3892x over previous
//
#include <hip/hip_runtime.h>
#include <hip/hip_bf16.h>
#include <cstddef>
#include <cstdint>

typedef unsigned short u16;
typedef unsigned int   u32;

#define Mtok  16384
#define Ncode 8192
#define Kdim  256
#define NSPLIT 8
#define NPER  (Ncode / NSPLIT)    // 1024 codes per split
#define NT    (NPER / 128)        // 8 column tiles of 128 per block
#define TH_MARGIN 2.0f            // window: 2*(bf16 err ~0.25 + trunc13 ~0.5..1)
#define RCHUNK 256                // full-rescue: codes per chunk
#define RNCH  (Ncode / RCHUNK)    // 32 chunks

typedef __bf16 bf16x8 __attribute__((ext_vector_type(8)));
typedef float  f32x4  __attribute__((ext_vector_type(4)));

#define LDSP(p) ((__attribute__((address_space(3))) void*)(p))
#define GPTR(p) ((const __attribute__((address_space(1))) void*)(p))

__device__ __forceinline__ u16 f2bf(float x) {
    __hip_bfloat16 h = __float2bfloat16(x);
    return *reinterpret_cast<u16*>(&h);
}

// ---------------------------------------------------------------------------
// Kernel 1: transpose z -> z_out (fp32), plus bf16 s = -2*z.
// Also zeroes the rescue counter (stream-ordered before k_merge).
__global__ __launch_bounds__(256) void k_prep(const float* __restrict__ z,
        float* __restrict__ z_out, u16* __restrict__ sh, int* __restrict__ count) {
    __shared__ float tile[32][33];
    const int b  = blockIdx.z;
    const int c0 = blockIdx.y * 32;
    const int p0 = blockIdx.x * 32;
    const int tx = threadIdx.x;   // 0..31
    const int ty = threadIdx.y;   // 0..7
    if (b == 0 && c0 == 0 && p0 == 0 && tx == 0 && ty == 0) count[0] = 0;
    const float* src = z + ((size_t)b * Kdim + c0) * 1024 + p0;
#pragma unroll
    for (int i = 0; i < 32; i += 8)
        tile[ty + i][tx] = src[(size_t)(ty + i) * 1024 + tx];
    __syncthreads();
#pragma unroll
    for (int i = 0; i < 32; i += 8) {
        const float v = tile[tx][ty + i];
        const size_t m = (size_t)b * 1024 + p0 + ty + i;
        const int    c = c0 + tx;
        z_out[m * Kdim + c] = v;
        sh[m * Kdim + c] = f2bf(-2.0f * v);
    }
}

// ---------------------------------------------------------------------------
// Kernel 2: per-code ||w||^2 plus bf16 wh. One wave per code row.
__global__ __launch_bounds__(64) void k_wsplit(const float* __restrict__ w,
        float* __restrict__ wnorm, u16* __restrict__ wh) {
    const int row  = blockIdx.x;
    const int lane = threadIdx.x;
    const float4 v = ((const float4*)(w + (size_t)row * Kdim))[lane];
    float s = v.x * v.x + v.y * v.y + v.z * v.z + v.w * v.w;
#pragma unroll
    for (int off = 32; off > 0; off >>= 1)
        s += __shfl_down(s, off, 64);
    if (lane == 0) wnorm[row] = s;
    ushort4 ph;
    u16* hp = (u16*)&ph;
    hp[0] = f2bf(v.x); hp[1] = f2bf(v.y); hp[2] = f2bf(v.z); hp[3] = f2bf(v.w);
    *(ushort4*)(wh + (size_t)row * Kdim + lane * 4) = ph;
}

// ---------------------------------------------------------------------------
// Kernel 3 (round-15): round-10 skeleton VERBATIM (BK=64 double-buffered
// pipeline, NSPL=8, 0-conflict swizzle, k_mfma measured 129.5us) with the
// top-3 bookkeeping swapped for PACKED KEYS (proven r11/r12):
//   key = (bits(max(d,0)) & ~0x1FFF) | global_code_idx
// Positive-float compare == unsigned, so sorted-3 insert = 5 min/max ops
// (vs ~11 cmp/cndmask), state 40 -> 24 regs, butterfly = 3 shfl + 5 ops,
// 3 partial arrays instead of 5, fmin-only k_merge. r10's measured top
// consumer was VALUBusy 51% -- this targets exactly that.
// NSPL=8 kept: r12 showed split-count multiplies A-refetch + epilogue cost.
// Round rr (kk=(rr&3)*64): vmcnt(4) -> s_barrier -> [rq==0: acc=wn] ->
// 2x{8 ds_read + 16 MFMA} (setprio) -> lgkmcnt(0) -> s_barrier ->
// stage(rr+2 -> buf[rr&1], 4 loads). Round 31: vmcnt(0).
__global__ __launch_bounds__(256, 2) void k_mfma(
        const u16* __restrict__ sh, const u16* __restrict__ wh,
        const float* __restrict__ wnorm,
        float* __restrict__ pk1, float* __restrict__ pk2, float* __restrict__ pk3) {
    __shared__ __align__(16) u16 Bh[2][128 * 64];
    __shared__ __align__(16) float wn_lds[NPER];
    const int tid  = threadIdx.x;
    const int w    = tid >> 6;          // wave 0..3
    const int lane = tid & 63;
    const int l15  = lane & 15;
    const int q    = lane >> 4;         // 0..3
    const int y    = blockIdx.x & 7;    // n-split (XCD pin)
    const int x    = blockIdx.x >> 3;   // m-tile
    const int m0   = x * 128;
    const int n0   = y * NPER;
    const int srow8 = lane >> 3;        // staging: 8 rows x 8 16B-chunks
    const int sqg8  = (lane & 7) ^ srow8;  // pre-swizzled source chunk
    const int rsw   = l15 & 7;             // read-side row swizzle bits

    // ---- prologue: A fragments -> registers (direct global, un-swizzled) ---
    bf16x8 ah[8][2];
#pragma unroll
    for (int ks = 0; ks < 8; ++ks)
#pragma unroll
        for (int i = 0; i < 2; ++i) {
            const size_t ra = (size_t)(m0 + w * 32 + i * 16 + l15) * Kdim
                              + ks * 32 + q * 8;
            ah[ks][i] = *(const bf16x8*)(sh + ra);
        }
    // wnorm -> LDS: each lane 16B, wave-uniform LDS base (gload_lds rule)
    __builtin_amdgcn_global_load_lds(GPTR(wnorm + n0 + w * 256 + lane * 4),
                                     LDSP(wn_lds + w * 256), 16, 0, 0);
    // stage B for rounds 0 and 1 (K=0..63 and 64..127 of nt=0; 4 loads/wave)
#pragma unroll
    for (int rr = 0; rr < 2; ++rr) {
        const int kk = rr * 64;
#pragma unroll
        for (int t = 0; t < 4; ++t) {
            const int row = w * 32 + t * 8 + srow8;
            const size_t gb = (size_t)(n0 + row) * Kdim + kk + sqg8 * 8;
            __builtin_amdgcn_global_load_lds(GPTR(wh + gb),
                LDSP(&Bh[rr][(w * 32 + t * 8) * 64]), 16, 0, 0);
        }
    }

    // packed top-3 state per slot s=i*4+r -> row m0+w*32+i*16+q*4+r
    const float SENT = __uint_as_float(0x7F7FFFFFu);
    float k1[8], k2[8], k3[8];
#pragma unroll
    for (int s = 0; s < 8; ++s) { k1[s] = SENT; k2[s] = SENT; k3[s] = SENT; }

    f32x4 acc[2][8];
#pragma unroll 1
    for (int nt = 0; nt < NT; ++nt) {
        const int nb = n0 + nt * 128;
#pragma unroll
        for (int rq = 0; rq < 4; ++rq) {   // 4 rounds of K=64 per nt
            const int rr  = nt * 4 + rq;
            const int par = rr & 1;
            // vmcnt ledger: outstanding = stage(rr)[4] + stage(rr+1)[4];
            // round 0 additionally A(16)+wn(1) older; round 31: drain to 0.
            if (rr == NT * 4 - 1) {
                asm volatile("s_waitcnt vmcnt(0)" ::: "memory");
            } else {
                asm volatile("s_waitcnt vmcnt(4)" ::: "memory");
            }
            __builtin_amdgcn_s_barrier();   // all waves' stages for rr visible
            if (rq == 0) {
#pragma unroll
                for (int j = 0; j < 8; ++j) {
                    const float wv = wn_lds[nt * 128 + j * 16 + l15];
#pragma unroll
                    for (int i = 0; i < 2; ++i) {
                        acc[i][j][0] = wv; acc[i][j][1] = wv;
                        acc[i][j][2] = wv; acc[i][j][3] = wv;
                    }
                }
            }
            __builtin_amdgcn_s_setprio(1);
#pragma unroll
            for (int ks2 = 0; ks2 < 2; ++ks2) {
                const int kidx = rq * 2 + ks2;   // ah index (compile-time)
#pragma unroll
                for (int j = 0; j < 8; ++j) {
                    const int slot = (ks2 * 4 + q) ^ rsw;   // swizzled chunk
                    const bf16x8 bh_ = *(const bf16x8*)
                        &Bh[par][(j * 16 + l15) * 64 + slot * 8];
                    acc[0][j] = __builtin_amdgcn_mfma_f32_16x16x32_bf16(ah[kidx][0], bh_, acc[0][j], 0, 0, 0);
                    acc[1][j] = __builtin_amdgcn_mfma_f32_16x16x32_bf16(ah[kidx][1], bh_, acc[1][j], 0, 0, 0);
                }
            }
            __builtin_amdgcn_s_setprio(0);
            // all my ds_reads of buf[par] done (stage below can't overtake)
            asm volatile("s_waitcnt lgkmcnt(0)" ::: "memory");
            __builtin_amdgcn_s_barrier();   // all waves done reading buf[par]
            if (rr + 2 < NT * 4) {          // stage round rr+2 into buf[par]
                const int rr2 = rr + 2;
                const int nb2 = n0 + (rr2 >> 2) * 128;
                const int kk2 = (rr2 & 3) * 64;
#pragma unroll
                for (int t = 0; t < 4; ++t) {
                    const int row = w * 32 + t * 8 + srow8;
                    const size_t gb = (size_t)(nb2 + row) * Kdim + kk2 + sqg8 * 8;
                    __builtin_amdgcn_global_load_lds(GPTR(wh + gb),
                        LDSP(&Bh[par][(w * 32 + t * 8) * 64]), 16, 0, 0);
                }
            }
        }
        // packed top-3 insert: 8 ops/value (3 pack + 5 min/max)
#pragma unroll
        for (int i = 0; i < 2; ++i)
#pragma unroll
            for (int r = 0; r < 4; ++r) {
                const int s = i * 4 + r;
#pragma unroll
                for (int j = 0; j < 8; ++j) {
                    const u32 pb = (__float_as_uint(fmaxf(acc[i][j][r], 0.0f))
                                    & 0xFFFFE000u) | (u32)(nb + j * 16 + l15);
                    const float p = __uint_as_float(pb);
                    const float nk1 = fminf(k1[s], p);
                    const float nk2 = fminf(k2[s], fmaxf(k1[s], p));
                    const float nk3 = fminf(k3[s], fmaxf(k2[s], p));
                    k1[s] = nk1; k2[s] = nk2; k3[s] = nk3;
                }
            }
    }
    // butterfly merge of sorted triples across the 16 row-lanes
#pragma unroll
    for (int msk = 1; msk < 16; msk <<= 1) {
#pragma unroll
        for (int s = 0; s < 8; ++s) {
            const float b1 = __shfl_xor(k1[s], msk, 64);
            const float b2 = __shfl_xor(k2[s], msk, 64);
            const float b3 = __shfl_xor(k3[s], msk, 64);
            const float w1 = fminf(k1[s], b1);
            const float w2 = fminf(fmaxf(k1[s], b1), fminf(k2[s], b2));
            const float w3 = fminf(fminf(fmaxf(k2[s], b1), fmaxf(k1[s], b2)),
                                   fminf(k3[s], b3));
            k1[s] = w1; k2[s] = w2; k3[s] = w3;
        }
    }
    if (l15 == 0) {
#pragma unroll
        for (int i = 0; i < 2; ++i)
#pragma unroll
            for (int r = 0; r < 4; ++r) {
                const int s = i * 4 + r;
                const int m = m0 + w * 32 + i * 16 + q * 4 + r;
                pk1[(size_t)y * Mtok + m] = k1[s];
                pk2[(size_t)y * Mtok + m] = k2[s];
                pk3[(size_t)y * Mtok + m] = k3[s];
            }
    }
}

// ---------------------------------------------------------------------------
// Kernel 4: merge split top-3 keys -> resolved idx OR candidates OR full.
// Keys are value-packed (idx in low 13 bits) -> pure fmin compares.
// Completeness: window code is split-rank<=2 (captured via pk1/pk2) or its
// split's pk3 < lim (detected -> full rescue).
__global__ __launch_bounds__(256) void k_merge(
        const float* __restrict__ pk1, const float* __restrict__ pk2,
        const float* __restrict__ pk3, int* __restrict__ fidx,
        int* __restrict__ flag, int* __restrict__ cands,
        int* __restrict__ list, int* __restrict__ count) {
    const int t = blockIdx.x * 256 + threadIdx.x;
    float gb1 = __uint_as_float(0x7F7FFFFFu);
#pragma unroll
    for (int s = 0; s < NSPLIT; ++s)
        gb1 = fminf(gb1, pk1[(size_t)s * Mtok + t]);
    const float lim = __uint_as_float(__float_as_uint(gb1) & 0xFFFFE000u)
                      + TH_MARGIN;
    bool full = false;
    int nc = 0;
#pragma unroll
    for (int s = 0; s < NSPLIT; ++s) {
        const float a1 = pk1[(size_t)s * Mtok + t];
        const float a2 = pk2[(size_t)s * Mtok + t];
        const float a3 = pk3[(size_t)s * Mtok + t];
        if (a1 < lim) cands[(size_t)t * 16 + nc++] = (int)(__float_as_uint(a1) & 0x1FFFu);
        if (a2 < lim) cands[(size_t)t * 16 + nc++] = (int)(__float_as_uint(a2) & 0x1FFFu);
        full = full || (a3 < lim);
    }
    fidx[t] = (int)(__float_as_uint(gb1) & 0x1FFFu);
    int f = 0;
    if (full) {
        f = -1;
        const int p = atomicAdd(count, 1);
        list[p] = t;
    } else if (nc >= 2) {
        f = nc;
    }
    flag[t] = f;
}

// ---------------------------------------------------------------------------
// Kernel 5: exact fp32 full rescore (rare safety net), over code chunks.
__global__ __launch_bounds__(256) void k_rescue(
        const float* __restrict__ z_out, const float* __restrict__ w,
        const float* __restrict__ wnorm, const int* __restrict__ list,
        const int* __restrict__ count,
        float* __restrict__ pcv, int* __restrict__ pci) {
    const int bx   = blockIdx.x;       // chunk
    const int tid  = threadIdx.x;
    const int wv   = tid >> 6;
    const int lane = tid & 63;
    __shared__ float rv[4];
    __shared__ int   ri[4];
    const int cnt = count[0];
    for (int it = blockIdx.y; it < cnt; it += gridDim.y) {
        const int t = list[it];
        const float4 zv = *(const float4*)(z_out + (size_t)t * Kdim + lane * 4);
        float bd = 3.0e38f; int bn = 0x7fffffff;
#pragma unroll 4
        for (int i = 0; i < RCHUNK / 4; ++i) {
            const int n = bx * RCHUNK + i * 4 + wv;
            const float4 wr = *(const float4*)(w + (size_t)n * Kdim + lane * 4);
            float s = fmaf(wr.x, zv.x, fmaf(wr.y, zv.y,
                      fmaf(wr.z, zv.z, wr.w * zv.w)));
#pragma unroll
            for (int msk = 1; msk < 64; msk <<= 1)
                s += __shfl_xor(s, msk, 64);
            const float d = wnorm[n] - 2.0f * s;
            if (d < bd) { bd = d; bn = n; }
        }
        if (lane == 0) { rv[wv] = bd; ri[wv] = bn; }
        __syncthreads();
        if (tid == 0) {
            float b = rv[0]; int bi = ri[0];
#pragma unroll
            for (int k = 1; k < 4; ++k)
                if (rv[k] < b || (rv[k] == b && ri[k] < bi)) { b = rv[k]; bi = ri[k]; }
            pcv[(size_t)t * RNCH + bx] = b;
            pci[(size_t)t * RNCH + bx] = bi;
        }
        __syncthreads();
    }
}

// ---------------------------------------------------------------------------
// Kernel 6: gather z_q = weight[idx] + per-token resolution. One wave/token.
// flag==0: fidx. flag==n: exact fp32 rescore of the n candidates (wave
// butterfly dot, all lanes converge). flag==-1: merge RNCH full partials.
__global__ __launch_bounds__(256) void k_gather(
        const float* __restrict__ z_out, const float* __restrict__ w,
        const float* __restrict__ wnorm, const int* __restrict__ fidx,
        const int* __restrict__ flag, const int* __restrict__ cands,
        const float* __restrict__ pcv, const int* __restrict__ pci,
        float* __restrict__ zq, float* __restrict__ idx_out) {
    const int token = blockIdx.x * 4 + (threadIdx.x >> 6);
    const int lane  = threadIdx.x & 63;
    const int f = flag[token];
    int bi = fidx[token];
    if (f == -1) {
        float v = 3.0e38f; int ii = 0x7fffffff;
        if (lane < RNCH) {
            v  = pcv[(size_t)token * RNCH + lane];
            ii = pci[(size_t)token * RNCH + lane];
        }
#pragma unroll
        for (int msk = 1; msk < 64; msk <<= 1) {
            const float ov = __shfl_xor(v, msk, 64);
            const int   oi = __shfl_xor(ii, msk, 64);
            if (ov < v || (ov == v && oi < ii)) { v = ov; ii = oi; }
        }
        bi = ii;
    } else if (f > 0) {
        const float4 zv = *(const float4*)(z_out + (size_t)token * Kdim + lane * 4);
        float bv = 3.0e38f; int bn = 0x7fffffff;
#pragma unroll 1
        for (int c = 0; c < f; ++c) {
            const int n = cands[(size_t)token * 16 + c];
            const float4 wr = *(const float4*)(w + (size_t)n * Kdim + lane * 4);
            float s = fmaf(wr.x, zv.x, fmaf(wr.y, zv.y,
                      fmaf(wr.z, zv.z, wr.w * zv.w)));
#pragma unroll
            for (int msk = 1; msk < 64; msk <<= 1)
                s += __shfl_xor(s, msk, 64);
            const float d = wnorm[n] - 2.0f * s;
            if (d < bv || (d == bv && n < bn)) { bv = d; bn = n; }
        }
        bi = bn;   // uniform: butterfly gives all lanes the full sum
    }
    const float4 u = *(const float4*)(w + (size_t)bi * Kdim + lane * 4);
    *(float4*)(zq + (size_t)token * Kdim + lane * 4) = u;
    if (lane == 0) idx_out[token] = (float)bi;
}

// ---------------------------------------------------------------------------
extern "C" void kernel_launch(void* const* d_in, const int* in_sizes, int n_in,
                              void* d_out, int out_size, void* d_ws, size_t ws_size,
                              hipStream_t stream) {
    const float* z = (const float*)d_in[0];
    const float* w = (const float*)d_in[1];

    float* z_out  = (float*)d_out;                          // [16384, 256]
    float* zq     = z_out + (size_t)Mtok * Kdim;            // [16384, 256]
    float* idxout = zq + (size_t)Mtok * Kdim;               // [16384]

    char* ws = (char*)d_ws;
    u16*   sh    = (u16*)ws;                       ws += (size_t)Mtok * Kdim * 2;
    u16*   wh    = (u16*)ws;                       ws += (size_t)Ncode * Kdim * 2;
    float* wnorm = (float*)ws;                     ws += (size_t)Ncode * 4;
    float* pk1   = (float*)ws;                     ws += (size_t)NSPLIT * Mtok * 4;
    float* pk2   = (float*)ws;                     ws += (size_t)NSPLIT * Mtok * 4;
    float* pk3   = (float*)ws;                     ws += (size_t)NSPLIT * Mtok * 4;
    int*   fidx  = (int*)ws;                       ws += (size_t)Mtok * 4;
    int*   flag  = (int*)ws;                       ws += (size_t)Mtok * 4;
    int*   cands = (int*)ws;                       ws += (size_t)Mtok * 16 * 4;
    int*   list  = (int*)ws;                       ws += (size_t)Mtok * 4;
    int*   count = (int*)ws;                       ws += 256;
    float* pcv   = (float*)ws;                     ws += (size_t)Mtok * RNCH * 4;
    int*   pci   = (int*)ws;                       ws += (size_t)Mtok * RNCH * 4;

    k_prep<<<dim3(1024 / 32, Kdim / 32, 16), dim3(32, 8), 0, stream>>>(z, z_out, sh, count);
    k_wsplit<<<dim3(Ncode), dim3(64), 0, stream>>>(w, wnorm, wh);
    k_mfma<<<dim3(128 * NSPLIT), dim3(256), 0, stream>>>(sh, wh, wnorm,
                                                         pk1, pk2, pk3);
    k_merge<<<dim3(Mtok / 256), dim3(256), 0, stream>>>(pk1, pk2, pk3,
                                                        fidx, flag, cands, list, count);
    k_rescue<<<dim3(RNCH, 64), dim3(256), 0, stream>>>(z_out, w, wnorm, list, count,
                                                       pcv, pci);
    k_gather<<<dim3(Mtok / 4), dim3(256), 0, stream>>>(z_out, w, wnorm, fidx, flag,
                                                       cands, pcv, pci, zq, idxout);
}